// Round 14
// baseline (270.068 us; speedup 1.0000x reference)
//
#include <hip/hip_runtime.h>
#include <hip/hip_fp16.h>
#include <math.h>

namespace {
constexpr int NCOL = 384, NROW = 64, NVIEW = 16, NSAMP = 256;
constexpr float DET_U = 1.2f, DET_V = 1.2f;
constexpr float ISO = 500.0f, SDD = 1000.0f;
constexpr double SQRT3 = 1.7320508075688772;
constexpr float DT = (float)SQRT3;                          // RAY_LEN / NSAMP
constexpr float T0 = (float)(500.0 - SQRT3 * 256.0 * 0.5); // ISO - RAY_LEN/2
constexpr size_t VOL_N = 256u * 256u * 256u;               // 16.7M voxels
}

__device__ __forceinline__ void axis_interval(float p0, float d, float LO, float HI,
                                              float& tlo, float& thi) {
    if (fabsf(d) < 1e-7f) {
        if (p0 < LO || p0 > HI) { tlo = 1e30f; thi = -1e30f; }
        else                    { tlo = -1e30f; thi = 1e30f; }
    } else {
        const float r = 1.0f / d;
        const float t1 = (LO - p0) * r, t2 = (HI - p0) * r;
        tlo = fminf(t1, t2); thi = fmaxf(t1, t2);
    }
}

__device__ __forceinline__ float sample_shell(const float* __restrict__ vol,
                                              float vx, float vy, float vz) {
    if (!(vx > -1.0f && vx < 256.0f && vy > -1.0f && vy < 256.0f &&
          vz > -1.0f && vz < 256.0f))
        return 0.0f;
    const float fx0 = floorf(vx), fy0 = floorf(vy), fz0 = floorf(vz);
    const int x0 = (int)fx0, y0 = (int)fy0, z0 = (int)fz0;
    const float fx = vx - fx0, fy = vy - fy0, fz = vz - fz0;
    float sum = 0.0f;
    #pragma unroll
    for (int dzz = 0; dzz < 2; ++dzz) {
        const float wz = dzz ? fz : 1.0f - fz;
        const int zi = z0 + dzz;
        #pragma unroll
        for (int dyy = 0; dyy < 2; ++dyy) {
            const float wy = dyy ? fy : 1.0f - fy;
            const int yi = y0 + dyy;
            #pragma unroll
            for (int dxx = 0; dxx < 2; ++dxx) {
                const float wx = dxx ? fx : 1.0f - fx;
                const int xi = x0 + dxx;
                if ((unsigned)xi < 256u && (unsigned)yi < 256u && (unsigned)zi < 256u)
                    sum += wz * wy * wx * vol[(zi << 16) | (yi << 8) | xi];
            }
        }
    }
    return sum;
}

struct Spans { int g0, s0, s1, g1; float dx, dy, dz, bx, by, bz; float cb, sb; };

__device__ __forceinline__ Spans ray_setup(const float* __restrict__ angles, int tid) {
    Spans sp;
    const int col = tid % NCOL;
    const int rv  = tid / NCOL;
    const int row = rv % NROW;
    const int view = rv / NROW;

    const float beta = angles[view];
    const float cb = cosf(beta), sb = sinf(beta);
    sp.cb = cb; sp.sb = sb;
    const float u = (col - NCOL * 0.5f + 0.5f) * DET_U;
    const float v = (row - NROW * 0.5f + 0.5f) * DET_V;

    const float sx = ISO * cb, sy = ISO * sb;               // source (z=0)
    const float detx = -(SDD - ISO) * cb - u * sb;
    const float dety = -(SDD - ISO) * sb + u * cb;
    const float detz = v;

    float dx = detx - sx, dy = dety - sy, dz = detz;
    const float inv = 1.0f / sqrtf(dx * dx + dy * dy + dz * dz);
    dx *= inv; dy *= inv; dz *= inv;
    sp.dx = dx; sp.dy = dy; sp.dz = dz;
    sp.bx = sx + 127.5f; sp.by = sy + 127.5f; sp.bz = 127.5f;

    float xl, xh, yl, yh, zl, zh;
    axis_interval(sp.bx, dx, 0.01f, 254.99f, xl, xh);
    axis_interval(sp.by, dy, 0.01f, 254.99f, yl, yh);
    axis_interval(sp.bz, dz, 0.01f, 254.99f, zl, zh);
    const float tin  = fmaxf(xl, fmaxf(yl, zl));
    const float tout = fminf(xh, fminf(yh, zh));

    axis_interval(sp.bx, dx, -1.05f, 256.05f, xl, xh);
    axis_interval(sp.by, dy, -1.05f, 256.05f, yl, yh);
    axis_interval(sp.bz, dz, -1.05f, 256.05f, zl, zh);
    const float glo = fmaxf(xl, fmaxf(yl, zl));
    const float ghi = fminf(xh, fminf(yh, zh));

    const float invdt = 1.0f / DT;
    float g0f = floorf((glo - T0) * invdt - 0.5f);
    float g1f = ceilf((ghi - T0) * invdt - 0.5f) + 1.0f;
    float s0f = ceilf((tin - T0) * invdt - 0.5f + 0.01f);
    float s1f = floorf((tout - T0) * invdt - 0.5f - 0.01f) + 1.0f;
    int g0 = (int)fminf(fmaxf(g0f, 0.0f), 256.0f);
    int g1 = (int)fminf(fmaxf(g1f, 0.0f), 256.0f);
    int s0 = (int)fminf(fmaxf(s0f, 0.0f), 256.0f);
    int s1 = (int)fminf(fmaxf(s1f, 0.0f), 256.0f);
    s0 = max(s0, g0); s1 = min(s1, g1);
    if (s1 < s0) { s0 = g0; s1 = g0; }
    sp.g0 = g0; sp.s0 = s0; sp.s1 = s1; sp.g1 = g1;
    return sp;
}

__device__ __forceinline__ float zlerp_u(unsigned u, float fc) {
    __half2 q; *reinterpret_cast<unsigned*>(&q) = u;
    const float lo = __low2float(q), hi = __high2float(q);
    return fmaf(fc, hi - lo, lo);
}

// ---------- pack AP: APd[z][y][a] = {zpair(a), zpair(a+1)},  APt[z][x][b] = {zpair(b), zpair(b+1)}
__global__ __launch_bounds__(256) void packAP_kernel(const float* __restrict__ vol,
                                                     uint2* __restrict__ APd,
                                                     uint2* __restrict__ APt) {
    __shared__ __half2 lds[33][34];   // [y][x] z-pairs, +1 halo in each dim
    const int z = blockIdx.z, z1 = (z < 255) ? z + 1 : 255;
    const int x0 = blockIdx.x * 32, y0 = blockIdx.y * 32;
    const int tx = threadIdx.x, ty = threadIdx.y;           // 32 x 8
    const int tid = ty * 32 + tx;
    const float* s0 = vol + (z  << 16);
    const float* s1 = vol + (z1 << 16);
    for (int idx = tid; idx < 33 * 33; idx += 256) {
        const int yy = idx / 33, xx = idx - yy * 33;
        const int gy = min(y0 + yy, 255), gx = min(x0 + xx, 255);
        const int g = (gy << 8) | gx;
        lds[yy][xx] = __floats2half2_rn(s0[g], s1[g]);
    }
    __syncthreads();
    uint2* Dp = APd + (z << 16);
    #pragma unroll
    for (int i = 0; i < 32; i += 8) {
        const int yy = ty + i;
        __half2 e0 = lds[yy][tx], e1 = lds[yy][tx + 1];
        uint2 q;
        q.x = *reinterpret_cast<unsigned*>(&e0);
        q.y = *reinterpret_cast<unsigned*>(&e1);
        Dp[((y0 + yy) << 8) | (x0 + tx)] = q;
    }
    uint2* Tp = APt + (z << 16);
    #pragma unroll
    for (int i = 0; i < 32; i += 8) {
        const int r = ty + i;                                // x-row
        __half2 e0 = lds[tx][r], e1 = lds[tx + 1][r];        // zpair(y), zpair(y+1)
        uint2 q;
        q.x = *reinterpret_cast<unsigned*>(&e0);
        q.y = *reinterpret_cast<unsigned*>(&e1);
        Tp[((x0 + r) << 8) | (y0 + tx)] = q;
    }
}

// per-sample pipeline state (named members -> registers)
struct SmpA { float fa, fb, fc; uint2 r0, r1; };

// ---------- main: a-pair + z-pair dual layout, 2 loads/sample ----------------
__global__ __launch_bounds__(256) void projector3d_ap_kernel(
    const float* __restrict__ vol,       // fp32 original (shell path)
    const uint2* __restrict__ APd,       // a-inner = x
    const uint2* __restrict__ APt,       // a-inner = y
    const float* __restrict__ angles,
    float* __restrict__ out)
{
    const int tid = blockIdx.x * 256 + threadIdx.x;

    const Spans sp = ray_setup(angles, tid);
    const float dx = sp.dx, dy = sp.dy, dz = sp.dz;
    const float bx = sp.bx, by = sp.by, bz = sp.bz;

    const bool useT = fabsf(sp.cb) > fabsf(sp.sb);
    const uint2* __restrict__ Pm = useT ? APt : APd;
    const float da = useT ? dy : dx, db = useT ? dx : dy;
    const float ba = useT ? by : bx, bb = useT ? bx : by;

    float acc = 0.0f;

    for (int s = sp.g0; s < sp.s0; ++s) {
        const float t = T0 + (s + 0.5f) * DT;
        acc += sample_shell(vol, fmaf(t, dx, bx), fmaf(t, dy, by), fmaf(t, dz, bz));
    }

    auto LOADS = [&](SmpA& S, int si) {
        const float t = T0 + (si + 0.5f) * DT;
        const float va = fmaf(t, da, ba), vb = fmaf(t, db, bb), vc = fmaf(t, dz, bz);
        const float a0 = floorf(va), b0 = floorf(vb), c0 = floorf(vc);
        S.fa = va - a0; S.fb = vb - b0; S.fc = vc - c0;
        const uint2* p = Pm + (((int)c0 << 16) | ((int)b0 << 8) | (int)a0);
        S.r0 = p[0]; S.r1 = p[256];
    };
    auto CONS = [&](const SmpA& S) -> float {
        const float v00 = zlerp_u(S.r0.x, S.fc), v01 = zlerp_u(S.r0.y, S.fc);
        const float v10 = zlerp_u(S.r1.x, S.fc), v11 = zlerp_u(S.r1.y, S.fc);
        const float c0 = fmaf(S.fa, v01 - v00, v00);
        const float c1 = fmaf(S.fa, v11 - v10, v10);
        return fmaf(S.fb, c1 - c0, c0);
    };

    {
        int s = sp.s0;
        const int s1 = sp.s1;
        if (s < s1) {
            SmpA A, B;
            LOADS(A, s);
            if (s + 1 < s1) {
                LOADS(B, s + 1);
                s += 2;
                for (; s + 1 < s1; s += 2) {
                    acc += CONS(A); LOADS(A, s);
                    acc += CONS(B); LOADS(B, s + 1);
                }
                if (s < s1) {
                    acc += CONS(A); LOADS(A, s);
                    acc += CONS(B);
                    acc += CONS(A);
                } else {
                    acc += CONS(A);
                    acc += CONS(B);
                }
            } else {
                acc += CONS(A);
            }
        }
    }

    for (int s2 = sp.s1; s2 < sp.g1; ++s2) {
        const float t = T0 + (s2 + 0.5f) * DT;
        acc += sample_shell(vol, fmaf(t, dx, bx), fmaf(t, dy, by), fmaf(t, dz, bz));
    }

    out[tid] = acc * DT;
}

// ---------- fallback A: z-pair dual (round-13, 255us total) ------------------
__global__ __launch_bounds__(256) void packBoth_kernel(const float* __restrict__ vol,
                                                       __half2* __restrict__ P,
                                                       __half2* __restrict__ PT) {
    __shared__ __half2 tile[32][33];
    const int z = blockIdx.z;
    const int z1 = (z < 255) ? z + 1 : 255;
    const int x0 = blockIdx.x * 32, y0 = blockIdx.y * 32;
    const int tx = threadIdx.x, ty = threadIdx.y;   // 32 x 8
    const float* s0 = vol + (z  << 16);
    const float* s1 = vol + (z1 << 16);
    __half2* Pp = P + (z << 16);
    #pragma unroll
    for (int i = 0; i < 32; i += 8) {
        const int idx = ((y0 + ty + i) << 8) | (x0 + tx);
        const __half2 h = __floats2half2_rn(s0[idx], s1[idx]);
        Pp[idx] = h;
        tile[ty + i][tx] = h;
    }
    __syncthreads();
    __half2* Tp = PT + (z << 16);
    #pragma unroll
    for (int i = 0; i < 32; i += 8)
        Tp[((x0 + ty + i) << 8) | (y0 + tx)] = tile[tx][ty + i];
}

__device__ __forceinline__ float zlerp(__half2 q, float fc) {
    const float lo = __low2float(q), hi = __high2float(q);
    return fmaf(fc, hi - lo, lo);
}

struct Smp { float fa, fb, fc; __half2 q00, q01, q10, q11; };

__global__ __launch_bounds__(256) void projector3d_zp_kernel(
    const float* __restrict__ vol,
    const __half2* __restrict__ P,
    const __half2* __restrict__ PT,
    const float* __restrict__ angles,
    float* __restrict__ out)
{
    const int tid = blockIdx.x * 256 + threadIdx.x;
    const Spans sp = ray_setup(angles, tid);
    const float dx = sp.dx, dy = sp.dy, dz = sp.dz;
    const float bx = sp.bx, by = sp.by, bz = sp.bz;
    const bool useT = fabsf(sp.cb) > fabsf(sp.sb);
    const __half2* __restrict__ Pm = useT ? PT : P;
    const float da = useT ? dy : dx, db = useT ? dx : dy;
    const float ba = useT ? by : bx, bb = useT ? bx : by;

    float acc = 0.0f;
    for (int s = sp.g0; s < sp.s0; ++s) {
        const float t = T0 + (s + 0.5f) * DT;
        acc += sample_shell(vol, fmaf(t, dx, bx), fmaf(t, dy, by), fmaf(t, dz, bz));
    }
    auto LOADS = [&](Smp& S, int si) {
        const float t = T0 + (si + 0.5f) * DT;
        const float va = fmaf(t, da, ba), vb = fmaf(t, db, bb), vc = fmaf(t, dz, bz);
        const float a0 = floorf(va), b0 = floorf(vb), c0 = floorf(vc);
        S.fa = va - a0; S.fb = vb - b0; S.fc = vc - c0;
        const __half2* p = Pm + (((int)c0 << 16) | ((int)b0 << 8) | (int)a0);
        S.q00 = p[0]; S.q01 = p[1]; S.q10 = p[256]; S.q11 = p[257];
    };
    auto CONS = [&](const Smp& S) -> float {
        const float v00 = zlerp(S.q00, S.fc), v01 = zlerp(S.q01, S.fc);
        const float v10 = zlerp(S.q10, S.fc), v11 = zlerp(S.q11, S.fc);
        const float c0 = fmaf(S.fa, v01 - v00, v00);
        const float c1 = fmaf(S.fa, v11 - v10, v10);
        return fmaf(S.fb, c1 - c0, c0);
    };
    {
        int s = sp.s0;
        const int s1 = sp.s1;
        if (s < s1) {
            Smp A, B;
            LOADS(A, s);
            if (s + 1 < s1) {
                LOADS(B, s + 1);
                s += 2;
                for (; s + 1 < s1; s += 2) {
                    acc += CONS(A); LOADS(A, s);
                    acc += CONS(B); LOADS(B, s + 1);
                }
                if (s < s1) {
                    acc += CONS(A); LOADS(A, s);
                    acc += CONS(B);
                    acc += CONS(A);
                } else {
                    acc += CONS(A);
                    acc += CONS(B);
                }
            } else {
                acc += CONS(A);
            }
        }
    }
    for (int s2 = sp.s1; s2 < sp.g1; ++s2) {
        const float t = T0 + (s2 + 0.5f) * DT;
        acc += sample_shell(vol, fmaf(t, dx, bx), fmaf(t, dy, by), fmaf(t, dz, bz));
    }
    out[tid] = acc * DT;
}

// ---------- fallback B: plain fp32 -------------------------------------------
__global__ __launch_bounds__(256) void projector3d_f32_kernel(
    const float* __restrict__ vol, const float* __restrict__ angles,
    float* __restrict__ out)
{
    const int tid = blockIdx.x * 256 + threadIdx.x;
    const Spans sp = ray_setup(angles, tid);
    const float dx = sp.dx, dy = sp.dy, dz = sp.dz;
    const float bx = sp.bx, by = sp.by, bz = sp.bz;
    float acc = 0.0f;
    for (int s = sp.g0; s < sp.s0; ++s) {
        const float t = T0 + (s + 0.5f) * DT;
        acc += sample_shell(vol, fmaf(t, dx, bx), fmaf(t, dy, by), fmaf(t, dz, bz));
    }
    #pragma unroll 4
    for (int s = sp.s0; s < sp.s1; ++s) {
        const float t = T0 + (s + 0.5f) * DT;
        const float vx = fmaf(t, dx, bx), vy = fmaf(t, dy, by), vz = fmaf(t, dz, bz);
        const float fx0 = floorf(vx), fy0 = floorf(vy), fz0 = floorf(vz);
        const int x0 = (int)fx0, y0 = (int)fy0, z0 = (int)fz0;
        const float fx = vx - fx0, fy = vy - fy0, fz = vz - fz0;
        const float* p = vol + ((z0 << 16) | (y0 << 8) | x0);
        const float v000 = p[0],     v001 = p[1];
        const float v010 = p[256],   v011 = p[257];
        const float v100 = p[65536], v101 = p[65537];
        const float v110 = p[65792], v111 = p[65793];
        const float c00 = fmaf(fx, v001 - v000, v000);
        const float c01 = fmaf(fx, v011 - v010, v010);
        const float c10 = fmaf(fx, v101 - v100, v100);
        const float c11 = fmaf(fx, v111 - v110, v110);
        const float c0 = fmaf(fy, c01 - c00, c00);
        const float c1 = fmaf(fy, c11 - c10, c10);
        acc += fmaf(fz, c1 - c0, c0);
    }
    for (int s = sp.s1; s < sp.g1; ++s) {
        const float t = T0 + (s + 0.5f) * DT;
        acc += sample_shell(vol, fmaf(t, dx, bx), fmaf(t, dy, by), fmaf(t, dz, bz));
    }
    out[tid] = acc * DT;
}

extern "C" void kernel_launch(void* const* d_in, const int* in_sizes, int n_in,
                              void* d_out, int out_size, void* d_ws, size_t ws_size,
                              hipStream_t stream) {
    const float* vol    = (const float*)d_in[0];
    const float* angles = (const float*)d_in[1];
    float* out = (float*)d_out;

    const int grid = (NVIEW * NROW * NCOL) / 256;       // 1536
    dim3 tgrid(8, 8, 256), tblk(32, 8);
    if (ws_size >= 2u * VOL_N * sizeof(uint2)) {        // 268 MB: a-pair + z-pair dual
        uint2* APd = (uint2*)d_ws;
        uint2* APt = APd + VOL_N;
        packAP_kernel<<<tgrid, tblk, 0, stream>>>(vol, APd, APt);
        projector3d_ap_kernel<<<grid, 256, 0, stream>>>(vol, APd, APt, angles, out);
    } else if (ws_size >= 2u * VOL_N * sizeof(__half2)) {   // 134 MB: z-pair dual
        __half2* P  = (__half2*)d_ws;
        __half2* PT = P + VOL_N;
        packBoth_kernel<<<tgrid, tblk, 0, stream>>>(vol, P, PT);
        projector3d_zp_kernel<<<grid, 256, 0, stream>>>(vol, P, PT, angles, out);
    } else {
        projector3d_f32_kernel<<<grid, 256, 0, stream>>>(vol, angles, out);
    }
}

// Round 15
// 211.999 us; speedup vs baseline: 1.2739x; 1.2739x over previous
//
#include <hip/hip_runtime.h>
#include <hip/hip_fp16.h>
#include <math.h>

namespace {
constexpr int NCOL = 384, NROW = 64, NVIEW = 16, NSAMP = 256;
constexpr float DET_U = 1.2f, DET_V = 1.2f;
constexpr float ISO = 500.0f, SDD = 1000.0f;
constexpr double SQRT3 = 1.7320508075688772;
constexpr float DT = (float)SQRT3;                          // RAY_LEN / NSAMP
constexpr float T0 = (float)(500.0 - SQRT3 * 256.0 * 0.5); // ISO - RAY_LEN/2
constexpr size_t VOL_N = 256u * 256u * 256u;               // 16.7M voxels
// z-restricted packed slab: rays only reach vz in [100.2, 154.8] (geometry
// constant, beta-independent: vz = 127.5 + t*v/||d||, |v|<=37.8, t<=722).
constexpr int Z0 = 96, ZS = 64;                            // slices [96,160)
constexpr size_t SLAB_N = (size_t)ZS * 256u * 256u;        // 4.2M elements
}

__device__ __forceinline__ void axis_interval(float p0, float d, float LO, float HI,
                                              float& tlo, float& thi) {
    if (fabsf(d) < 1e-7f) {
        if (p0 < LO || p0 > HI) { tlo = 1e30f; thi = -1e30f; }
        else                    { tlo = -1e30f; thi = 1e30f; }
    } else {
        const float r = 1.0f / d;
        const float t1 = (LO - p0) * r, t2 = (HI - p0) * r;
        tlo = fminf(t1, t2); thi = fmaxf(t1, t2);
    }
}

__device__ __forceinline__ float sample_shell(const float* __restrict__ vol,
                                              float vx, float vy, float vz) {
    if (!(vx > -1.0f && vx < 256.0f && vy > -1.0f && vy < 256.0f &&
          vz > -1.0f && vz < 256.0f))
        return 0.0f;
    const float fx0 = floorf(vx), fy0 = floorf(vy), fz0 = floorf(vz);
    const int x0 = (int)fx0, y0 = (int)fy0, z0 = (int)fz0;
    const float fx = vx - fx0, fy = vy - fy0, fz = vz - fz0;
    float sum = 0.0f;
    #pragma unroll
    for (int dzz = 0; dzz < 2; ++dzz) {
        const float wz = dzz ? fz : 1.0f - fz;
        const int zi = z0 + dzz;
        #pragma unroll
        for (int dyy = 0; dyy < 2; ++dyy) {
            const float wy = dyy ? fy : 1.0f - fy;
            const int yi = y0 + dyy;
            #pragma unroll
            for (int dxx = 0; dxx < 2; ++dxx) {
                const float wx = dxx ? fx : 1.0f - fx;
                const int xi = x0 + dxx;
                if ((unsigned)xi < 256u && (unsigned)yi < 256u && (unsigned)zi < 256u)
                    sum += wz * wy * wx * vol[(zi << 16) | (yi << 8) | xi];
            }
        }
    }
    return sum;
}

struct Spans { int g0, s0, s1, g1; float dx, dy, dz, bx, by, bz; float cb, sb; };

__device__ __forceinline__ Spans ray_setup(const float* __restrict__ angles, int tid) {
    Spans sp;
    const int col = tid % NCOL;
    const int rv  = tid / NCOL;
    const int row = rv % NROW;
    const int view = rv / NROW;

    const float beta = angles[view];
    const float cb = cosf(beta), sb = sinf(beta);
    sp.cb = cb; sp.sb = sb;
    const float u = (col - NCOL * 0.5f + 0.5f) * DET_U;
    const float v = (row - NROW * 0.5f + 0.5f) * DET_V;

    const float sx = ISO * cb, sy = ISO * sb;               // source (z=0)
    const float detx = -(SDD - ISO) * cb - u * sb;
    const float dety = -(SDD - ISO) * sb + u * cb;
    const float detz = v;

    float dx = detx - sx, dy = dety - sy, dz = detz;
    const float inv = 1.0f / sqrtf(dx * dx + dy * dy + dz * dz);
    dx *= inv; dy *= inv; dz *= inv;
    sp.dx = dx; sp.dy = dy; sp.dz = dz;
    sp.bx = sx + 127.5f; sp.by = sy + 127.5f; sp.bz = 127.5f;

    float xl, xh, yl, yh, zl, zh;
    axis_interval(sp.bx, dx, 0.01f, 254.99f, xl, xh);
    axis_interval(sp.by, dy, 0.01f, 254.99f, yl, yh);
    axis_interval(sp.bz, dz, 0.01f, 254.99f, zl, zh);
    const float tin  = fmaxf(xl, fmaxf(yl, zl));
    const float tout = fminf(xh, fminf(yh, zh));

    axis_interval(sp.bx, dx, -1.05f, 256.05f, xl, xh);
    axis_interval(sp.by, dy, -1.05f, 256.05f, yl, yh);
    axis_interval(sp.bz, dz, -1.05f, 256.05f, zl, zh);
    const float glo = fmaxf(xl, fmaxf(yl, zl));
    const float ghi = fminf(xh, fminf(yh, zh));

    const float invdt = 1.0f / DT;
    float g0f = floorf((glo - T0) * invdt - 0.5f);
    float g1f = ceilf((ghi - T0) * invdt - 0.5f) + 1.0f;
    float s0f = ceilf((tin - T0) * invdt - 0.5f + 0.01f);
    float s1f = floorf((tout - T0) * invdt - 0.5f - 0.01f) + 1.0f;
    int g0 = (int)fminf(fmaxf(g0f, 0.0f), 256.0f);
    int g1 = (int)fminf(fmaxf(g1f, 0.0f), 256.0f);
    int s0 = (int)fminf(fmaxf(s0f, 0.0f), 256.0f);
    int s1 = (int)fminf(fmaxf(s1f, 0.0f), 256.0f);
    s0 = max(s0, g0); s1 = min(s1, g1);
    if (s1 < s0) { s0 = g0; s1 = g0; }
    sp.g0 = g0; sp.s0 = s0; sp.s1 = s1; sp.g1 = g1;
    return sp;
}

__device__ __forceinline__ float zlerp_u(unsigned u, float fc) {
    __half2 q; *reinterpret_cast<unsigned*>(&q) = u;
    const float lo = __low2float(q), hi = __high2float(q);
    return fmaf(fc, hi - lo, lo);
}

// ---------- pack (z-restricted): APd[z'][y][a]={zpair(a),zpair(a+1)}, APt[z'][x][b] likewise
__global__ __launch_bounds__(256) void packAP_kernel(const float* __restrict__ vol,
                                                     uint2* __restrict__ APd,
                                                     uint2* __restrict__ APt) {
    __shared__ __half2 lds[33][34];   // [y][x] z-pairs, +1 halo
    const int z = Z0 + blockIdx.z;                          // 96..159
    const int z1 = (z < 255) ? z + 1 : 255;
    const int x0 = blockIdx.x * 32, y0 = blockIdx.y * 32;
    const int tx = threadIdx.x, ty = threadIdx.y;           // 32 x 8
    const int tid = ty * 32 + tx;
    const float* s0 = vol + (z  << 16);
    const float* s1 = vol + (z1 << 16);
    for (int idx = tid; idx < 33 * 33; idx += 256) {
        const int yy = idx / 33, xx = idx - yy * 33;
        const int gy = min(y0 + yy, 255), gx = min(x0 + xx, 255);
        const int g = (gy << 8) | gx;
        lds[yy][xx] = __floats2half2_rn(s0[g], s1[g]);
    }
    __syncthreads();
    uint2* Dp = APd + ((size_t)blockIdx.z << 16);
    #pragma unroll
    for (int i = 0; i < 32; i += 8) {
        const int yy = ty + i;
        __half2 e0 = lds[yy][tx], e1 = lds[yy][tx + 1];
        uint2 q;
        q.x = *reinterpret_cast<unsigned*>(&e0);
        q.y = *reinterpret_cast<unsigned*>(&e1);
        Dp[((y0 + yy) << 8) | (x0 + tx)] = q;
    }
    uint2* Tp = APt + ((size_t)blockIdx.z << 16);
    #pragma unroll
    for (int i = 0; i < 32; i += 8) {
        const int r = ty + i;                                // x-row
        __half2 e0 = lds[tx][r], e1 = lds[tx + 1][r];        // zpair(y), zpair(y+1)
        uint2 q;
        q.x = *reinterpret_cast<unsigned*>(&e0);
        q.y = *reinterpret_cast<unsigned*>(&e1);
        Tp[((x0 + r) << 8) | (y0 + tx)] = q;
    }
}

// per-sample pipeline state (named members -> registers)
struct SmpA { float fa, fb, fc; uint2 r0, r1; };

// ---------- main: a-pair + z-pair dual layout (z-restricted), 2 loads/sample -
__global__ __launch_bounds__(256) void projector3d_ap_kernel(
    const float* __restrict__ vol,       // fp32 original (shell path)
    const uint2* __restrict__ APd,       // a-inner = x
    const uint2* __restrict__ APt,       // a-inner = y
    const float* __restrict__ angles,
    float* __restrict__ out)
{
    const int tid = blockIdx.x * 256 + threadIdx.x;

    const Spans sp = ray_setup(angles, tid);
    const float dx = sp.dx, dy = sp.dy, dz = sp.dz;
    const float bx = sp.bx, by = sp.by, bz = sp.bz;

    const bool useT = fabsf(sp.cb) > fabsf(sp.sb);
    const uint2* __restrict__ Pm = useT ? APt : APd;
    const float da = useT ? dy : dx, db = useT ? dx : dy;
    const float ba = useT ? by : bx, bb = useT ? bx : by;

    float acc = 0.0f;

    for (int s = sp.g0; s < sp.s0; ++s) {
        const float t = T0 + (s + 0.5f) * DT;
        acc += sample_shell(vol, fmaf(t, dx, bx), fmaf(t, dy, by), fmaf(t, dz, bz));
    }

    auto LOADS = [&](SmpA& S, int si) {
        const float t = T0 + (si + 0.5f) * DT;
        const float va = fmaf(t, da, ba), vb = fmaf(t, db, bb), vc = fmaf(t, dz, bz);
        const float a0 = floorf(va), b0 = floorf(vb), c0 = floorf(vc);
        S.fa = va - a0; S.fb = vb - b0; S.fc = vc - c0;
        // z is analytically in [100,154]; clamp for memory safety only
        const int zi = min(max((int)c0, Z0), Z0 + ZS - 2) - Z0;
        const uint2* p = Pm + (((size_t)zi << 16) | ((int)b0 << 8) | (int)a0);
        S.r0 = p[0]; S.r1 = p[256];
    };
    auto CONS = [&](const SmpA& S) -> float {
        const float v00 = zlerp_u(S.r0.x, S.fc), v01 = zlerp_u(S.r0.y, S.fc);
        const float v10 = zlerp_u(S.r1.x, S.fc), v11 = zlerp_u(S.r1.y, S.fc);
        const float c0 = fmaf(S.fa, v01 - v00, v00);
        const float c1 = fmaf(S.fa, v11 - v10, v10);
        return fmaf(S.fb, c1 - c0, c0);
    };

    {
        int s = sp.s0;
        const int s1 = sp.s1;
        if (s < s1) {
            SmpA A, B;
            LOADS(A, s);
            if (s + 1 < s1) {
                LOADS(B, s + 1);
                s += 2;
                for (; s + 1 < s1; s += 2) {
                    acc += CONS(A); LOADS(A, s);
                    acc += CONS(B); LOADS(B, s + 1);
                }
                if (s < s1) {
                    acc += CONS(A); LOADS(A, s);
                    acc += CONS(B);
                    acc += CONS(A);
                } else {
                    acc += CONS(A);
                    acc += CONS(B);
                }
            } else {
                acc += CONS(A);
            }
        }
    }

    for (int s2 = sp.s1; s2 < sp.g1; ++s2) {
        const float t = T0 + (s2 + 0.5f) * DT;
        acc += sample_shell(vol, fmaf(t, dx, bx), fmaf(t, dy, by), fmaf(t, dz, bz));
    }

    out[tid] = acc * DT;
}

// ---------- fallback: plain fp32 ---------------------------------------------
__global__ __launch_bounds__(256) void projector3d_f32_kernel(
    const float* __restrict__ vol, const float* __restrict__ angles,
    float* __restrict__ out)
{
    const int tid = blockIdx.x * 256 + threadIdx.x;
    const Spans sp = ray_setup(angles, tid);
    const float dx = sp.dx, dy = sp.dy, dz = sp.dz;
    const float bx = sp.bx, by = sp.by, bz = sp.bz;
    float acc = 0.0f;
    for (int s = sp.g0; s < sp.s0; ++s) {
        const float t = T0 + (s + 0.5f) * DT;
        acc += sample_shell(vol, fmaf(t, dx, bx), fmaf(t, dy, by), fmaf(t, dz, bz));
    }
    #pragma unroll 4
    for (int s = sp.s0; s < sp.s1; ++s) {
        const float t = T0 + (s + 0.5f) * DT;
        const float vx = fmaf(t, dx, bx), vy = fmaf(t, dy, by), vz = fmaf(t, dz, bz);
        const float fx0 = floorf(vx), fy0 = floorf(vy), fz0 = floorf(vz);
        const int x0 = (int)fx0, y0 = (int)fy0, z0 = (int)fz0;
        const float fx = vx - fx0, fy = vy - fy0, fz = vz - fz0;
        const float* p = vol + ((z0 << 16) | (y0 << 8) | x0);
        const float v000 = p[0],     v001 = p[1];
        const float v010 = p[256],   v011 = p[257];
        const float v100 = p[65536], v101 = p[65537];
        const float v110 = p[65792], v111 = p[65793];
        const float c00 = fmaf(fx, v001 - v000, v000);
        const float c01 = fmaf(fx, v011 - v010, v010);
        const float c10 = fmaf(fx, v101 - v100, v100);
        const float c11 = fmaf(fx, v111 - v110, v110);
        const float c0 = fmaf(fy, c01 - c00, c00);
        const float c1 = fmaf(fy, c11 - c10, c10);
        acc += fmaf(fz, c1 - c0, c0);
    }
    for (int s = sp.s1; s < sp.g1; ++s) {
        const float t = T0 + (s + 0.5f) * DT;
        acc += sample_shell(vol, fmaf(t, dx, bx), fmaf(t, dy, by), fmaf(t, dz, bz));
    }
    out[tid] = acc * DT;
}

extern "C" void kernel_launch(void* const* d_in, const int* in_sizes, int n_in,
                              void* d_out, int out_size, void* d_ws, size_t ws_size,
                              hipStream_t stream) {
    const float* vol    = (const float*)d_in[0];
    const float* angles = (const float*)d_in[1];
    float* out = (float*)d_out;

    const int grid = (NVIEW * NROW * NCOL) / 256;       // 1536
    if (ws_size >= 2u * SLAB_N * sizeof(uint2)) {       // 67 MB: z-restricted dual a-pair
        uint2* APd = (uint2*)d_ws;
        uint2* APt = APd + SLAB_N;
        dim3 tgrid(8, 8, ZS), tblk(32, 8);
        packAP_kernel<<<tgrid, tblk, 0, stream>>>(vol, APd, APt);
        projector3d_ap_kernel<<<grid, 256, 0, stream>>>(vol, APd, APt, angles, out);
    } else {
        projector3d_f32_kernel<<<grid, 256, 0, stream>>>(vol, angles, out);
    }
}